// Round 1
// baseline (462.379 us; speedup 1.0000x reference)
//
#include <hip/hip_runtime.h>

// UnarySqrt scan: out_t = (1-tr)*x_t + tr ; tr' = out_t*(1-tr), over T=64 steps.
// Values are exact {0,1} floats, so float math reproduces the boolean logic exactly.
// Memory-bound: 256 MB in + 256 MB out. One thread per 4 channels (float4),
// coalesced across the N dimension for every time step.

__global__ __launch_bounds__(256) void UnarySqrt_kernel(
    const float4* __restrict__ in,      // [T, N/4] as float4
    const float4* __restrict__ trace0,  // [N/4] as float4
    float4* __restrict__ out,           // [T, N/4] as float4
    int stride,                          // N/4
    int T)
{
    int idx = blockIdx.x * blockDim.x + threadIdx.x;
    if (idx >= stride) return;

    float4 tr = trace0[idx];

    #pragma unroll 8
    for (int t = 0; t < T; ++t) {
        float4 x = in[(size_t)t * (size_t)stride + (size_t)idx];
        float4 o;
        o.x = (1.0f - tr.x) * x.x + tr.x;
        o.y = (1.0f - tr.y) * x.y + tr.y;
        o.z = (1.0f - tr.z) * x.z + tr.z;
        o.w = (1.0f - tr.w) * x.w + tr.w;
        out[(size_t)t * (size_t)stride + (size_t)idx] = o;
        // trace update uses the OLD trace value
        float4 ntr;
        ntr.x = o.x * (1.0f - tr.x);
        ntr.y = o.y * (1.0f - tr.y);
        ntr.z = o.z * (1.0f - tr.z);
        ntr.w = o.w * (1.0f - tr.w);
        tr = ntr;
    }
}

extern "C" void kernel_launch(void* const* d_in, const int* in_sizes, int n_in,
                              void* d_out, int out_size, void* d_ws, size_t ws_size,
                              hipStream_t stream) {
    const float* bits   = (const float*)d_in[0];  // [T, N]
    const float* trace0 = (const float*)d_in[1];  // [N]

    int N = in_sizes[1];
    int T = in_sizes[0] / N;
    int stride = N / 4;  // N = 1048576 -> divisible by 4

    int block = 256;
    int grid = (stride + block - 1) / block;

    UnarySqrt_kernel<<<grid, block, 0, stream>>>(
        (const float4*)bits,
        (const float4*)trace0,
        (float4*)d_out,
        stride, T);
}

// Round 3
// 453.971 us; speedup vs baseline: 1.0185x; 1.0185x over previous
//
#include <hip/hip_runtime.h>

// UnarySqrt scan over T=64 steps, N=2^20 channels, values are exact {0,1} floats.
// Bit identities:  out_t = tr | x_t  = tr + x_t*(1-tr)   (disjoint add, exact)
//                  tr'   = x_t & ~tr = x_t*(1-tr)
// so with p = x*(1-tr):  out = tr + p ; tr' = p.
//
// Memory-bound (256 MB in + 256 MB out). Round 1 was latency-bound at 30%
// occupancy (16 waves/CU cap with float4/thread). This version:
//  - float2/thread -> 524288 threads = 32 waves/CU (hardware cap)
//  - explicit prefetch of x[t+1] keeps >=1 independent load in flight per wave
//  - nontemporal stores keep the write stream from evicting input in L2/L3
// NOTE: __builtin_nontemporal_store requires a clang vector type, not HIP's
// float2 class -> use ext_vector_type(2).

typedef float v2f __attribute__((ext_vector_type(2)));

__global__ __launch_bounds__(256) void UnarySqrt_kernel(
    const v2f* __restrict__ in,      // [T, N/2] as v2f
    const v2f* __restrict__ trace0,  // [N/2] as v2f
    v2f* __restrict__ out,           // [T, N/2] as v2f
    int stride)                       // N/2
{
    int idx = blockIdx.x * blockDim.x + threadIdx.x;
    if (idx >= stride) return;

    v2f tr = trace0[idx];
    v2f x  = in[idx];  // prefetch t=0

    #pragma unroll 8
    for (int t = 0; t < 64; ++t) {
        v2f xn;
        if (t + 1 < 64) {
            xn = in[(size_t)(t + 1) * (size_t)stride + (size_t)idx];
        }
        // p = x*(1-tr); out = tr + p; tr' = p
        v2f p = x * (1.0f - tr);
        v2f o = tr + p;
        __builtin_nontemporal_store(o, &out[(size_t)t * (size_t)stride + (size_t)idx]);
        tr = p;
        x = xn;
    }
}

extern "C" void kernel_launch(void* const* d_in, const int* in_sizes, int n_in,
                              void* d_out, int out_size, void* d_ws, size_t ws_size,
                              hipStream_t stream) {
    const float* bits   = (const float*)d_in[0];  // [T, N]
    const float* trace0 = (const float*)d_in[1];  // [N]

    int N = in_sizes[1];
    int stride = N / 2;  // N = 1048576 -> divisible by 2

    int block = 256;
    int grid = (stride + block - 1) / block;

    UnarySqrt_kernel<<<grid, block, 0, stream>>>(
        (const v2f*)bits,
        (const v2f*)trace0,
        (v2f*)d_out,
        stride);
}